// Round 8
// baseline (111.502 us; speedup 1.0000x reference)
//
#include <hip/hip_runtime.h>

#define N 64
#define NPAD 65
#define ITERS 50
#define TEMP 12.5f
#define WEPS 1e-5f
#define QDIM 75
#define WDIM 5

// whole-wave rotate by one lane, VALU pipe (DPP): ctrl 0x134 = wave_rol:1, 0x13C = wave_ror:1
#define ROL(x) __int_as_float(__builtin_amdgcn_update_dpp(0, __float_as_int(x), 0x134, 0xF, 0xF, true))
#define ROR(x) __int_as_float(__builtin_amdgcn_update_dpp(0, __float_as_int(x), 0x13C, 0xF, 0xF, true))

__device__ __forceinline__ float waveReduceSum(float x) {
#pragma unroll
    for (int off = 32; off; off >>= 1) x += __shfl_xor(x, off, 64);
    return x;
}

// Systolic Sinkhorn: lane r owns row r (u-phase) and col r (v-phase) of K,
// stored as DIAGONALS KL[m]=K[r][r+dl*m], KR[m]=K[r][r+dr*(m+1)] so that the
// operand vector v/u circulates through the wave via wave_rol/ror DPP.
// The row-sum accumulates IN-LANE -> after the chain lane r holds u[r], which
// is exactly the v-phase's starting state: the iteration loop has ZERO LDS
// traffic, ZERO barriers, ZERO cross-lane reductions. Rotation direction is
// probed at runtime (no reliance on rol/ror naming conventions).
__global__ __launch_bounds__(64, 1) void emd_systolic(
    const float* __restrict__ sim,   // [B, 64, 64]
    const float* __restrict__ w1,    // [B, N]
    const float* __restrict__ w2,    // [E, W, Q, N] (transposed Q/W)
    float* __restrict__ out,         // [B]
    int B)
{
    __shared__ float S[N * NPAD];    // staging only (init + none in loop)

    const int lane = threadIdx.x;
    const int b    = blockIdx.x;
    const float* gm = sim + (size_t)b * N * N;

    // ---- probe rotation directions: after one ROL, lane holds id of source lane ----
    const int dl = (__builtin_amdgcn_update_dpp(0, lane, 0x134, 0xF, 0xF, true) - lane) & 63; // ±1 as 1 or 63
    const int dr = (__builtin_amdgcn_update_dpp(0, lane, 0x13C, 0xF, 0xF, true) - lane) & 63;

    // ---- stage sim into LDS (coalesced float4), padded for diagonal gathers ----
    const float4* g4 = (const float4*)gm;
#pragma unroll
    for (int t = 0; t < 16; ++t) {
        float4 x = g4[t * 64 + lane];
        int idx = t * 64 + lane;
        int r = idx >> 4;
        int c = (idx & 15) * 4;
        S[r * NPAD + c + 0] = x.x;
        S[r * NPAD + c + 1] = x.y;
        S[r * NPAD + c + 2] = x.z;
        S[r * NPAD + c + 3] = x.w;
    }
    __syncthreads();

    // ---- diagonal K fragments: K = exp(-cost/eps) = exp(20*(sim-1)) ----
    // u-phase row r:  KL[m] ~ col (r+dl*m), m=0..31;  KR[m] ~ col (r+dr*(m+1)), m=0..31
    // v-phase col c:  CL[m] ~ row (c+dl*m);           CR[m] ~ row (c+dr*(m+1))
    float KL[32], KR[32], CL[32], CR[32];
#pragma unroll
    for (int m = 0; m < 32; ++m) {
        int cL = (lane + dl * m) & 63;
        int cR = (lane + dr * (m + 1)) & 63;
        KL[m] = __expf((S[lane * NPAD + cL] - 1.0f) * 20.0f);
        KR[m] = __expf((S[lane * NPAD + cR] - 1.0f) * 20.0f);
        CL[m] = __expf((S[cL * NPAD + lane] - 1.0f) * 20.0f);
        CR[m] = __expf((S[cR * NPAD + lane] - 1.0f) * 20.0f);
    }
    // opaque pin: forbid sinking/remat of the exp chains into the loop
#pragma unroll
    for (int m = 0; m < 32; ++m) {
        asm volatile("" : "+v"(KL[m]));
        asm volatile("" : "+v"(KR[m]));
        asm volatile("" : "+v"(CL[m]));
        asm volatile("" : "+v"(CR[m]));
    }

    // ---- marginals: lane needs only its OWN row/col value ----
    float a_own = w1[(size_t)b * N + lane];
    a_own = fmaxf(a_own, 0.0f) + WEPS;
    a_own *= (float)N / waveReduceSum(a_own);

    const int e  = b / (QDIM * WDIM);
    const int rm = b % (QDIM * WDIM);
    const int q  = rm / WDIM, w = rm % WDIM;
    float b_own = w2[((((size_t)e * WDIM + w) * QDIM) + q) * N + lane];
    b_own = fmaxf(b_own, 0.0f) + WEPS;
    b_own *= (float)N / waveReduceSum(b_own);

    // ---- Sinkhorn: pure VALU/DPP loop ----
    float vv = 1.0f, u = 0.0f;
#pragma unroll 1
    for (int it = 0; it < ITERS; ++it) {
        // u[r] = a[r] / sum_c K[r][c] v[c]
        {
            float wL = vv, wR = vv;
            float accL = KL[0] * wL;
            float accR = 0.0f;
#pragma unroll
            for (int m = 1; m <= 32; ++m) {
                wR = ROR(wR);
                accR = fmaf(KR[m - 1], wR, accR);
                if (m <= 31) {
                    wL = ROL(wL);
                    accL = fmaf(KL[m], wL, accL);
                }
            }
            u = a_own * __builtin_amdgcn_rcpf(accL + accR);
        }
        // v[c] = b[c] / sum_r K[r][c] u[r]
        {
            float wL = u, wR = u;
            float accL = CL[0] * wL;
            float accR = 0.0f;
#pragma unroll
            for (int m = 1; m <= 32; ++m) {
                wR = ROR(wR);
                accR = fmaf(CR[m - 1], wR, accR);
                if (m <= 31) {
                    wL = ROL(wL);
                    accL = fmaf(CL[m], wL, accL);
                }
            }
            vv = b_own * __builtin_amdgcn_rcpf(accL + accR);
        }
    }

    // ---- score = sum_ij u_i K_ij sim_ij v_j, sim = 1 + log2(K)*ln2/20 ----
    {
        const float cc = 0.69314718056f / 20.0f;
        float wL = vv, wR = vv;
        float sL = KL[0] * fmaf(__log2f(KL[0]), cc, 1.0f) * wL;
        float sR = 0.0f;
#pragma unroll
        for (int m = 1; m <= 32; ++m) {
            wR = ROR(wR);
            sR = fmaf(KR[m - 1] * fmaf(__log2f(KR[m - 1]), cc, 1.0f), wR, sR);
            if (m <= 31) {
                wL = ROL(wL);
                sL = fmaf(KL[m] * fmaf(__log2f(KL[m]), cc, 1.0f), wL, sL);
            }
        }
        float tot = waveReduceSum(u * (sL + sR));
        if (lane == 0) out[b] = tot * (TEMP / (float)N);
    }
}

extern "C" void kernel_launch(void* const* d_in, const int* in_sizes, int n_in,
                              void* d_out, int out_size, void* d_ws, size_t ws_size,
                              hipStream_t stream) {
    const float* sim = (const float*)d_in[0];
    const float* w1  = (const float*)d_in[1];
    const float* w2  = (const float*)d_in[2];
    float* out       = (float*)d_out;
    const int B = in_sizes[0] / (N * N);   // 1500
    emd_systolic<<<B, 64, 0, stream>>>(sim, w1, w2, out, B);
}

// Round 9
// 99.978 us; speedup vs baseline: 1.1153x; 1.1153x over previous
//
#include <hip/hip_runtime.h>

#define N 64
#define ITERS 50
#define TEMP 12.5f
#define WEPS 1e-5f
#define QDIM 75
#define WDIM 5

typedef float v2f __attribute__((ext_vector_type(2)));

// guaranteed packed fp32 FMA (2 MACs / instruction, VOP3P)
static __device__ __forceinline__ v2f pkfma(v2f a, v2f b, v2f c) {
    v2f d;
    asm("v_pk_fma_f32 %0, %1, %2, %3" : "=v"(d) : "v"(a), "v"(b), "v"(c));
    return d;
}

// quad_perm butterfly within aligned 4-lane quads (VALU pipe)
#define DPP_XOR1(x) __int_as_float(__builtin_amdgcn_update_dpp(0, __float_as_int(x), 0xB1, 0xF, 0xF, true))
#define DPP_XOR2(x) __int_as_float(__builtin_amdgcn_update_dpp(0, __float_as_int(x), 0x4E, 0xF, 0xF, true))

__device__ __forceinline__ float waveReduceSum(float x) {
#pragma unroll
    for (int off = 32; off; off >>= 1) x += __shfl_xor(x, off, 64);
    return x;
}

// One wave per problem. Lane L = 4g+s owns a 4x16 tile of K (rows 4g..4g+3 x
// cols 16s..16s+15) and the transposed tile for the K^T phase, packed as v2f
// for v_pk_fma_f32. Per phase: 4 ds_read_b128 + 32 pk-FMA + quad DPP reduce +
// 1 ds_write. LDS = 512B (U,V only). Verified mapping from R7 (absmax 0.0).
__global__ __launch_bounds__(64, 1) void emd_pk(
    const float* __restrict__ sim,   // [B, 64, 64]
    const float* __restrict__ w1,    // [B, N]
    const float* __restrict__ w2,    // [E, W, Q, N] (transposed Q/W)
    float* __restrict__ out,         // [B]
    int B)
{
    __shared__ __align__(16) float S[128];   // S[0..63] = U, S[64..127] = V

    const int lane = threadIdx.x;
    const int b    = blockIdx.x;
    const int g    = lane >> 2;      // row-group base 4g
    const int s    = lane & 3;       // col-segment base 16s
    const float* gm = sim + (size_t)b * N * N;

    // ---- K fragments from global (16KB matrix, L1/L2 resident) ----
    // Kr2[k][m] = {K[4g+k][16s+2m], K[4g+k][16s+2m+1]}
    // Kc2[k][m] = {K[16s+2m][4g+k], K[16s+2m+1][4g+k]},  K = exp(20*(sim-1))
    v2f Kr2[4][8], Kc2[4][8];
#pragma unroll
    for (int k = 0; k < 4; ++k)
#pragma unroll
        for (int m = 0; m < 4; ++m) {
            float4 x = *(const float4*)(gm + (4 * g + k) * N + 16 * s + 4 * m);
            Kr2[k][2 * m + 0][0] = __expf((x.x - 1.0f) * 20.0f);
            Kr2[k][2 * m + 0][1] = __expf((x.y - 1.0f) * 20.0f);
            Kr2[k][2 * m + 1][0] = __expf((x.z - 1.0f) * 20.0f);
            Kr2[k][2 * m + 1][1] = __expf((x.w - 1.0f) * 20.0f);
        }
#pragma unroll
    for (int j = 0; j < 16; ++j) {
        float4 x = *(const float4*)(gm + (16 * s + j) * N + 4 * g);
        Kc2[0][j >> 1][j & 1] = __expf((x.x - 1.0f) * 20.0f);
        Kc2[1][j >> 1][j & 1] = __expf((x.y - 1.0f) * 20.0f);
        Kc2[2][j >> 1][j & 1] = __expf((x.z - 1.0f) * 20.0f);
        Kc2[3][j >> 1][j & 1] = __expf((x.w - 1.0f) * 20.0f);
    }
    // opaque pin: forbid sinking/remat of the exp chains into the loop
#pragma unroll
    for (int k = 0; k < 4; ++k)
#pragma unroll
        for (int m = 0; m < 8; ++m) {
            asm volatile("" : "+v"(Kr2[k][m]));
            asm volatile("" : "+v"(Kc2[k][m]));
        }

    // ---- marginals: lane needs only its OWN row/col value ----
    float a_own = w1[(size_t)b * N + lane];
    a_own = fmaxf(a_own, 0.0f) + WEPS;
    a_own *= (float)N / waveReduceSum(a_own);

    const int e  = b / (QDIM * WDIM);
    const int rm = b % (QDIM * WDIM);
    const int q  = rm / WDIM, w = rm % WDIM;
    float b_own = w2[((((size_t)e * WDIM + w) * QDIM) + q) * N + lane];
    b_own = fmaxf(b_own, 0.0f) + WEPS;
    b_own *= (float)N / waveReduceSum(b_own);

    S[64 + lane] = 1.0f;   // V init
    __syncthreads();

    float u = 0.0f;
#pragma unroll 1
    for (int it = 0; it < ITERS; ++it) {
        // ---- u-phase: u[r] = a[r]/sum_c K[r][c] v[c]; lane outputs row=lane ----
        {
            const float4* V4 = (const float4*)&S[64 + 16 * s];
            float4 x0 = V4[0], x1 = V4[1], x2 = V4[2], x3 = V4[3];
            v2f vv[8] = {{x0.x, x0.y}, {x0.z, x0.w}, {x1.x, x1.y}, {x1.z, x1.w},
                         {x2.x, x2.y}, {x2.z, x2.w}, {x3.x, x3.y}, {x3.z, x3.w}};
            v2f acc0 = {0, 0}, acc1 = {0, 0}, acc2 = {0, 0}, acc3 = {0, 0};
#pragma unroll
            for (int m = 0; m < 8; ++m) {
                acc0 = pkfma(Kr2[0][m], vv[m], acc0);
                acc1 = pkfma(Kr2[1][m], vv[m], acc1);
                acc2 = pkfma(Kr2[2][m], vv[m], acc2);
                acc3 = pkfma(Kr2[3][m], vv[m], acc3);
            }
            float s0 = acc0[0] + acc0[1], s1 = acc1[0] + acc1[1];
            float s2 = acc2[0] + acc2[1], s3 = acc3[0] + acc3[1];
            s0 += DPP_XOR1(s0); s1 += DPP_XOR1(s1); s2 += DPP_XOR1(s2); s3 += DPP_XOR1(s3);
            s0 += DPP_XOR2(s0); s1 += DPP_XOR2(s1); s2 += DPP_XOR2(s2); s3 += DPP_XOR2(s3);
            float ab = (s & 1) ? s1 : s0;
            float cd = (s & 1) ? s3 : s2;
            float se = (s & 2) ? cd : ab;
            u = a_own * __builtin_amdgcn_rcpf(se);
            S[lane] = u;   // U[lane]
        }
        __syncthreads();

        // ---- v-phase: v[c] = b[c]/sum_i K[i][c] u[i]; lane outputs col=lane ----
        {
            const float4* U4 = (const float4*)&S[16 * s];
            float4 x0 = U4[0], x1 = U4[1], x2 = U4[2], x3 = U4[3];
            v2f uu[8] = {{x0.x, x0.y}, {x0.z, x0.w}, {x1.x, x1.y}, {x1.z, x1.w},
                         {x2.x, x2.y}, {x2.z, x2.w}, {x3.x, x3.y}, {x3.z, x3.w}};
            v2f acc0 = {0, 0}, acc1 = {0, 0}, acc2 = {0, 0}, acc3 = {0, 0};
#pragma unroll
            for (int m = 0; m < 8; ++m) {
                acc0 = pkfma(Kc2[0][m], uu[m], acc0);
                acc1 = pkfma(Kc2[1][m], uu[m], acc1);
                acc2 = pkfma(Kc2[2][m], uu[m], acc2);
                acc3 = pkfma(Kc2[3][m], uu[m], acc3);
            }
            float s0 = acc0[0] + acc0[1], s1 = acc1[0] + acc1[1];
            float s2 = acc2[0] + acc2[1], s3 = acc3[0] + acc3[1];
            s0 += DPP_XOR1(s0); s1 += DPP_XOR1(s1); s2 += DPP_XOR1(s2); s3 += DPP_XOR1(s3);
            s0 += DPP_XOR2(s0); s1 += DPP_XOR2(s1); s2 += DPP_XOR2(s2); s3 += DPP_XOR2(s3);
            float ab = (s & 1) ? s1 : s0;
            float cd = (s & 1) ? s3 : s2;
            float se = (s & 2) ? cd : ab;
            S[64 + lane] = b_own * __builtin_amdgcn_rcpf(se);   // V[lane]
        }
        __syncthreads();
    }

    // ---- score = sum_ij u_i K_ij sim_ij v_j; sim = 1 + log2(K)*ln2/20 ----
    {
        float4 u4 = *(const float4*)&S[4 * g];           // U[4g..4g+3]
        const float4* V4 = (const float4*)&S[64 + 16 * s];
        float4 x0 = V4[0], x1 = V4[1], x2 = V4[2], x3 = V4[3];
        float vj[16] = {x0.x, x0.y, x0.z, x0.w, x1.x, x1.y, x1.z, x1.w,
                        x2.x, x2.y, x2.z, x2.w, x3.x, x3.y, x3.z, x3.w};
        float uk[4] = {u4.x, u4.y, u4.z, u4.w};
        const float c = 0.69314718056f / 20.0f;
        float p = 0.0f;
#pragma unroll
        for (int k = 0; k < 4; ++k) {
            float rs = 0.0f;
#pragma unroll
            for (int j = 0; j < 16; ++j) {
                float kk = Kr2[k][j >> 1][j & 1];
                float sv = fmaf(__log2f(kk), c, 1.0f);   // sim_ij
                rs = fmaf(kk * sv, vj[j], rs);
            }
            p = fmaf(uk[k], rs, p);
        }
        float tot = waveReduceSum(p);
        if (lane == 0) out[b] = tot * (TEMP / (float)N);
    }
}

extern "C" void kernel_launch(void* const* d_in, const int* in_sizes, int n_in,
                              void* d_out, int out_size, void* d_ws, size_t ws_size,
                              hipStream_t stream) {
    const float* sim = (const float*)d_in[0];
    const float* w1  = (const float*)d_in[1];
    const float* w2  = (const float*)d_in[2];
    float* out       = (float*)d_out;
    const int B = in_sizes[0] / (N * N);   // 1500
    emd_pk<<<B, 64, 0, stream>>>(sim, w1, w2, out, B);
}